// Round 6
// baseline (653.487 us; speedup 1.0000x reference)
//
#include <hip/hip_runtime.h>

// GCN 3-layer forward, fp32. N=100000 nodes, E=1.6M edges, HID=128, N_CLS=40.
// Workspace layout: Y[N*128] f32 | H[N*128] f32 | csr[E] i32 | rowptr[N+1] i32 |
// deg[N] i32 | cursor[N] i32 | norm[N] f32 | maskflag i32 | part[nb] i32

__global__ void k_deg(const int* __restrict__ dst, int* __restrict__ deg, int E) {
    int e = blockIdx.x * 256 + threadIdx.x;
    if (e < E) atomicAdd(&deg[dst[e]], 1);
}

// --- parallel prefix sum over deg (3 kernels, 1024 elements/block) ---
__global__ __launch_bounds__(256) void k_part(const int* __restrict__ deg,
                                              int* __restrict__ part, int n) {
    __shared__ int red[256];
    int t = threadIdx.x;
    int base = blockIdx.x * 1024 + t * 4;
    int s = 0;
#pragma unroll
    for (int j = 0; j < 4; ++j) {
        int i = base + j;
        if (i < n) s += deg[i];
    }
    red[t] = s;
    __syncthreads();
    for (int off = 128; off > 0; off >>= 1) {
        if (t < off) red[t] += red[t + off];
        __syncthreads();
    }
    if (t == 0) part[blockIdx.x] = red[0];
}

__global__ __launch_bounds__(256) void k_scanpart(int* __restrict__ part,
                                                  int* __restrict__ rowptr,
                                                  int nb, int n) {
    __shared__ int buf[1024];
    int t = threadIdx.x;
    for (int i = t; i < nb; i += 256) buf[i] = part[i];
    __syncthreads();
    if (t == 0) {
        int run = 0;
        for (int i = 0; i < nb; ++i) {
            int v = buf[i];
            buf[i] = run;
            run += v;
        }
        rowptr[n] = run;  // == E
    }
    __syncthreads();
    for (int i = t; i < nb; i += 256) part[i] = buf[i];
}

__global__ __launch_bounds__(256) void k_rowptr(const int* __restrict__ deg,
                                                const int* __restrict__ part,
                                                int* __restrict__ rowptr,
                                                float* __restrict__ normv, int n) {
    __shared__ int ts[256];
    int t = threadIdx.x;
    int base = blockIdx.x * 1024 + t * 4;
    int d[4];
    int s = 0;
#pragma unroll
    for (int j = 0; j < 4; ++j) {
        int i = base + j;
        d[j] = (i < n) ? deg[i] : 0;
        s += d[j];
    }
    ts[t] = s;
    __syncthreads();
    for (int off = 1; off < 256; off <<= 1) {
        int v = (t >= off) ? ts[t - off] : 0;
        __syncthreads();
        ts[t] += v;
        __syncthreads();
    }
    int run = part[blockIdx.x] + ((t == 0) ? 0 : ts[t - 1]);
#pragma unroll
    for (int j = 0; j < 4; ++j) {
        int i = base + j;
        if (i < n) {
            rowptr[i] = run;
            normv[i] = 1.0f / fmaxf((float)d[j], 1.0f);
            run += d[j];
        }
    }
}

__global__ void k_scatter(const int* __restrict__ src, const int* __restrict__ dst,
                          const int* __restrict__ rowptr, int* __restrict__ cursor,
                          int* __restrict__ csr, int E) {
    int e = blockIdx.x * 256 + threadIdx.x;
    if (e < E) {
        int d = dst[e];
        int p = atomicAdd(&cursor[d], 1);
        csr[rowptr[d] + p] = src[e];
    }
}

// Detect mask dtype: any word >1 in first 1024 words -> packed bytes (bool).
__global__ void k_maskdet(const unsigned* __restrict__ m, int* __restrict__ flag) {
    unsigned v = m[blockIdx.x * 256 + threadIdx.x];
    if (v > 1u) atomicOr(flag, 1);
}

// Y[r][c] = sum_k X[r][k] * W[k][c].  K=128 in four 32-wide chunks:
// LDS = Xs 16KB + Ws 16KB(BN=128)/8KB(BN=64) -> 3+ blocks/CU (vs 2 before).
// PACK: if PACK, only cols < wcols are stored, row stride = wcols (layer 3:
// 16MB buffer instead of 25.6MB). Otherwise stride = BN.
template<int BN, bool PACK>
__global__ __launch_bounds__(256, 3) void k_gemm(const float* __restrict__ X,
                                                 const float* __restrict__ Wg,
                                                 float* __restrict__ Y,
                                                 int nrows, int wcols) {
    constexpr int TN = BN / 16;  // 8 or 4
    __shared__ float Xs[128][32];
    __shared__ float Ws[32][BN];
    int t = threadIdx.x;
    int bm = blockIdx.x * 128;
    int tx = t & 15, ty = t >> 4;
    int sw = (ty & 3) << 2;

    float acc[8][TN];
#pragma unroll
    for (int i = 0; i < 8; ++i)
#pragma unroll
        for (int j = 0; j < TN; ++j) acc[i][j] = 0.0f;

    for (int kc = 0; kc < 128; kc += 32) {
        // stage X chunk: 128 rows x 8 float4
        for (int idx = t; idx < 128 * 8; idx += 256) {
            int row = idx >> 3, k4 = idx & 7;
            int grow = bm + row;
            if (grow >= nrows) grow = nrows - 1;
            float4 v = *(const float4*)(X + (size_t)grow * 128 + kc + k4 * 4);
            int kk2 = (k4 * 4) ^ (((row >> 3) & 3) << 2);
            *(float4*)&Xs[row][kk2] = v;
        }
        // stage W chunk
        if (BN == 128) {
            for (int idx = t; idx < 32 * 32; idx += 256) {
                int k = idx >> 5, c4 = idx & 31;
                *(float4*)&Ws[k][c4 * 4] =
                    *(const float4*)(Wg + (size_t)(kc + k) * 128 + c4 * 4);
            }
        } else {
            for (int idx = t; idx < 32 * BN; idx += 256) {
                int k = idx / BN, c = idx % BN;
                Ws[k][c] = (c < wcols) ? Wg[(size_t)(kc + k) * wcols + c] : 0.0f;
            }
        }
        __syncthreads();

        for (int k = 0; k < 32; k += 4) {
            float4 a4[8];
#pragma unroll
            for (int i = 0; i < 8; ++i)
                a4[i] = *(const float4*)&Xs[ty * 8 + i][k ^ sw];
#pragma unroll
            for (int kk = 0; kk < 4; ++kk) {
                float b[TN];
                *(float4*)&b[0] = *(const float4*)&Ws[k + kk][tx * 4];
                if (BN == 128)
                    *(float4*)&b[4] = *(const float4*)&Ws[k + kk][64 + tx * 4];
#pragma unroll
                for (int i = 0; i < 8; ++i) {
                    float a = ((const float*)&a4[i])[kk];
#pragma unroll
                    for (int j = 0; j < TN; ++j) acc[i][j] += a * b[j];
                }
            }
        }
        __syncthreads();
    }

    int ld = PACK ? wcols : BN;
#pragma unroll
    for (int i = 0; i < 8; ++i) {
        int r = bm + ty * 8 + i;
        if (r < nrows) {
            if (!PACK || tx * 4 < 40)
                *(float4*)(Y + (size_t)r * ld + tx * 4) = *(const float4*)&acc[i][0];
            if (BN == 128)
                *(float4*)(Y + (size_t)r * ld + 64 + tx * 4) = *(const float4*)&acc[i][4];
        }
    }
}

// SpMM, one WAVE per dst node, float2 per lane (512B row per instruction).
// 4 nodes per 256-thread block, unroll 4. mflag: 0 -> int32 mask, 1 -> bytes.
template<bool ACT>
__global__ __launch_bounds__(256) void k_spmmw(const float* __restrict__ Y,
                       const int* __restrict__ rowptr, const int* __restrict__ csr,
                       const float* __restrict__ normv, const float* __restrict__ bias,
                       const void* __restrict__ mask, const int* __restrict__ mflag,
                       float* __restrict__ H, int N) {
    int wid = threadIdx.x >> 6;
    int lane = threadIdx.x & 63;
    int i = blockIdx.x * 4 + wid;
    if (i >= N) return;
    int c = lane * 2;
    int lo = rowptr[i], hi = rowptr[i + 1];
    float2 acc = {0.0f, 0.0f};
    int e = lo;
    for (; e + 3 < hi; e += 4) {
        int s0 = csr[e], s1 = csr[e + 1], s2 = csr[e + 2], s3 = csr[e + 3];
        float2 v0 = *(const float2*)(Y + (size_t)s0 * 128 + c);
        float2 v1 = *(const float2*)(Y + (size_t)s1 * 128 + c);
        float2 v2 = *(const float2*)(Y + (size_t)s2 * 128 + c);
        float2 v3 = *(const float2*)(Y + (size_t)s3 * 128 + c);
        acc.x += v0.x + v1.x + v2.x + v3.x;
        acc.y += v0.y + v1.y + v2.y + v3.y;
    }
    for (; e < hi; ++e) {
        float2 v = *(const float2*)(Y + (size_t)csr[e] * 128 + c);
        acc.x += v.x;
        acc.y += v.y;
    }
    float nrm = normv[i];
    float2 b = *(const float2*)&bias[c];
    float vx = acc.x * nrm + b.x;
    float vy = acc.y * nrm + b.y;
    if (ACT) {
        vx = fmaxf(vx, 0.0f);
        vy = fmaxf(vy, 0.0f);
        size_t j = (size_t)i * 128 + c;
        bool k0, k1;
        if (*mflag != 0) {
            const unsigned char* m = (const unsigned char*)mask;
            k0 = m[j] != 0; k1 = m[j + 1] != 0;
        } else {
            const int* m = (const int*)mask;
            k0 = m[j] != 0; k1 = m[j + 1] != 0;
        }
        vx = k0 ? vx * 2.0f : 0.0f;  // KEEP=0.5 -> /0.5
        vy = k1 ? vy * 2.0f : 0.0f;
    }
    *(float2*)(H + (size_t)i * 128 + c) = make_float2(vx, vy);
}

// Layer-3 SpMM: wave per node, lanes 0..19 hold float2 (40 cols), Y stride 40.
__global__ __launch_bounds__(256) void k_spmm40w(const float* __restrict__ Y,
                        const int* __restrict__ rowptr, const int* __restrict__ csr,
                        const float* __restrict__ normv, const float* __restrict__ bias,
                        float* __restrict__ H, int N, int width) {
    int wid = threadIdx.x >> 6;
    int lane = threadIdx.x & 63;
    int i = blockIdx.x * 4 + wid;
    if (i >= N) return;
    int c = lane * 2;
    if (c >= width) return;
    int lo = rowptr[i], hi = rowptr[i + 1];
    float2 acc = {0.0f, 0.0f};
    int e = lo;
    for (; e + 3 < hi; e += 4) {
        int s0 = csr[e], s1 = csr[e + 1], s2 = csr[e + 2], s3 = csr[e + 3];
        float2 v0 = *(const float2*)(Y + (size_t)s0 * 40 + c);
        float2 v1 = *(const float2*)(Y + (size_t)s1 * 40 + c);
        float2 v2 = *(const float2*)(Y + (size_t)s2 * 40 + c);
        float2 v3 = *(const float2*)(Y + (size_t)s3 * 40 + c);
        acc.x += v0.x + v1.x + v2.x + v3.x;
        acc.y += v0.y + v1.y + v2.y + v3.y;
    }
    for (; e < hi; ++e) {
        float2 v = *(const float2*)(Y + (size_t)csr[e] * 40 + c);
        acc.x += v.x;
        acc.y += v.y;
    }
    float nrm = normv[i];
    float vx = acc.x * nrm + bias[c];
    float vy = acc.y * nrm + bias[c + 1];
    *(float2*)(H + (size_t)i * width + c) = make_float2(vx, vy);
}

extern "C" void kernel_launch(void* const* d_in, const int* in_sizes, int n_in,
                              void* d_out, int out_size, void* d_ws, size_t ws_size,
                              hipStream_t stream) {
    const float* feat = (const float*)d_in[0];
    const int* src = (const int*)d_in[1];
    const int* dst = (const int*)d_in[2];
    const void* mask1 = d_in[3];
    const void* mask2 = d_in[4];
    const float* w0 = (const float*)d_in[5];
    const float* b0 = (const float*)d_in[6];
    const float* w1 = (const float*)d_in[7];
    const float* b1 = (const float*)d_in[8];
    const float* w2 = (const float*)d_in[9];
    const float* b2 = (const float*)d_in[10];
    int N = in_sizes[0] / 128;
    int E = in_sizes[1];
    int ncls = in_sizes[10];  // 40

    float* out = (float*)d_out;
    float* Y = (float*)d_ws;
    float* H = Y + (size_t)N * 128;
    int* csr = (int*)(H + (size_t)N * 128);
    int* rowptr = csr + E;
    int* deg = rowptr + (N + 1);
    int* cursor = deg + N;
    float* normv = (float*)(cursor + N);
    int* mflag = (int*)(normv + N);
    int* part = mflag + 1;

    int nb = (N + 1023) / 1024;  // 98

    hipMemsetAsync(deg, 0, (size_t)N * 4, stream);
    hipMemsetAsync(cursor, 0, (size_t)N * 4, stream);
    hipMemsetAsync(mflag, 0, 4, stream);
    k_maskdet<<<4, 256, 0, stream>>>((const unsigned*)mask1, mflag);
    int eb = (E + 255) / 256;
    k_deg<<<eb, 256, 0, stream>>>(dst, deg, E);
    k_part<<<nb, 256, 0, stream>>>(deg, part, N);
    k_scanpart<<<1, 256, 0, stream>>>(part, rowptr, nb, N);
    k_rowptr<<<nb, 256, 0, stream>>>(deg, part, rowptr, normv, N);
    k_scatter<<<eb, 256, 0, stream>>>(src, dst, rowptr, cursor, csr, E);

    int gb = (N + 127) / 128;
    int sb = (N + 3) / 4;
    k_gemm<128, false><<<gb, 256, 0, stream>>>(feat, w0, Y, N, 128);
    k_spmmw<true><<<sb, 256, 0, stream>>>(Y, rowptr, csr, normv, b0, mask1, mflag, H, N);
    k_gemm<128, false><<<gb, 256, 0, stream>>>(H, w1, Y, N, 128);
    k_spmmw<true><<<sb, 256, 0, stream>>>(Y, rowptr, csr, normv, b1, mask2, mflag, H, N);
    k_gemm<64, true><<<gb, 256, 0, stream>>>(H, w2, Y, N, ncls);
    k_spmm40w<<<sb, 256, 0, stream>>>(Y, rowptr, csr, normv, b2, out, N, ncls);
}